// Round 5
// baseline (123.064 us; speedup 1.0000x reference)
//
#include <hip/hip_runtime.h>
#include <hip/hip_bf16.h>

// out[b,n] = sum_k x[b,k] * M[k,n],  M[k,n] = sign(k, k^n) * w[k^n]
// P=6,Q=0,R=0 -> metric all +1, sign = reorder parity only.
//
// out^T = M^T (A) @ x^T (B) via mfma_f32_16x16x32_bf16 (layout validated in
// round 4, absmax 0.25):
//   A-frag: lane l -> row a=l&15, k=(l>>4)*8+e  (frag-ordered in d_ws)
//   B-frag: lane l -> col b=l&15, k=(l>>4)*8+e  = 8 CONTIGUOUS floats of x row b
//           -> loaded straight from global as two float4, no LDS at all.
//   C/D   : D[m=(l>>4)*4+reg][n=l&15] -> lane's 4 regs = 4 consecutive out cols
//           of one batch row; the wave's 4 g-groups complete full 64B lines.

#define DIM 64
#define TPB 256            // 4 waves
#define ROWS 256           // rows per block (64 per wave)

typedef __attribute__((ext_vector_type(8))) short  bf16x8;
typedef __attribute__((ext_vector_type(4))) float  f32x4;

__device__ __forceinline__ unsigned short f2bf(float v) {
    __hip_bfloat16 hb = __float2bfloat16(v);
    return *reinterpret_cast<unsigned short*>(&hb);
}

// Mt[(kc*4+ab)*64 + lane] = 16B A-fragment slice for mfma block (kc, ab):
// elem e -> A[a = ab*16 + (l&15)][k = kc*32 + (l>>4)*8 + e], A = M^T.
__global__ void build_Mt(const float* __restrict__ w, unsigned short* __restrict__ Mt) {
    int t = threadIdx.x + blockIdx.x * blockDim.x;   // 0..4095
    if (t >= 8 * 64 * 8) return;
    int f  = t >> 9;
    int kc = f >> 2, ab = f & 3;
    int rem = t & 511;
    int l = rem >> 3, e = rem & 7;
    int k = kc * 32 + ((l >> 4) << 3) + e;
    int a = (ab << 4) + (l & 15);
    int j = k ^ a;
    int aa = k >> 1, cnt = 0;
    while (aa) { cnt += __popc(aa & j); aa >>= 1; }
    float v = (cnt & 1) ? -w[j] : w[j];
    Mt[t] = f2bf(v);
}

__global__ __launch_bounds__(TPB, 4)   // VGPR cap 128 -> 16 waves/CU
void gp_main_kernel(const float* __restrict__ x,
                    const unsigned short* __restrict__ Mt,
                    float* __restrict__ out) {
    const int tid  = threadIdx.x;
    const int lane = tid & 63;
    const int wv   = tid >> 6;
    const int r15  = lane & 15;
    const int g    = lane >> 4;          // k-quarter within fragment

    // ---- A-fragments (tiny, L2-resident after first blocks) ----
    bf16x8 af[2][4];
    const bf16x8* __restrict__ Mtv = (const bf16x8*)Mt;
    #pragma unroll
    for (int kc = 0; kc < 2; ++kc)
        #pragma unroll
        for (int ab = 0; ab < 4; ++ab)
            af[kc][ab] = Mtv[(kc * 4 + ab) * 64 + lane];

    const long long rowbase = (long long)blockIdx.x * ROWS + (long long)wv * 64;

    // ---- issue ALL 16 B-source loads up front (T14: deep vmcnt prefetch) ----
    // raw[bb][kc*2+h]: floats [kc*32 + g*8 + h*4, +4) of row rowbase+bb*16+r15
    float4 raw[4][4];
    #pragma unroll
    for (int bb = 0; bb < 4; ++bb) {
        const float4* __restrict__ p =
            (const float4*)(x + (rowbase + bb * 16 + r15) * DIM) + g * 2;
        raw[bb][0] = p[0];
        raw[bb][1] = p[1];
        raw[bb][2] = p[8];    // kc=1: +32 floats = +8 float4
        raw[bb][3] = p[9];
    }

    float4* __restrict__ outp = (float4*)out;

    #pragma unroll
    for (int bb = 0; bb < 4; ++bb) {
        // convert this chunk's 16 floats -> two bf16x8 B-fragments
        bf16x8 bfr[2];
        #pragma unroll
        for (int kc = 0; kc < 2; ++kc) {
            const float* s = (const float*)&raw[bb][kc * 2];
            bf16x8 t;
            #pragma unroll
            for (int e = 0; e < 8; ++e) t[e] = (short)f2bf(s[e]);
            bfr[kc] = t;
        }

        f32x4 acc[4];
        #pragma unroll
        for (int ab = 0; ab < 4; ++ab) acc[ab] = (f32x4){0.f, 0.f, 0.f, 0.f};
        #pragma unroll
        for (int kc = 0; kc < 2; ++kc)
            #pragma unroll
            for (int ab = 0; ab < 4; ++ab)
                acc[ab] = __builtin_amdgcn_mfma_f32_16x16x32_bf16(
                    af[kc][ab], bfr[kc], acc[ab], 0, 0, 0);

        const long long rg = rowbase + bb * 16 + r15;
        #pragma unroll
        for (int ab = 0; ab < 4; ++ab)
            outp[rg * 16 + ab * 4 + g] =
                make_float4(acc[ab][0], acc[ab][1], acc[ab][2], acc[ab][3]);
    }
}

extern "C" void kernel_launch(void* const* d_in, const int* in_sizes, int n_in,
                              void* d_out, int out_size, void* d_ws, size_t ws_size,
                              hipStream_t stream) {
    const float* x = (const float*)d_in[0];
    const float* w = (const float*)d_in[1];
    float* out = (float*)d_out;
    unsigned short* Mt = (unsigned short*)d_ws;   // 8 KB frag-ordered M^T

    int nrows = in_sizes[0] / DIM;                // 1048576
    int nblocks = nrows / ROWS;                   // 4096 (exact)

    build_Mt<<<16, 256, 0, stream>>>(w, Mt);
    gp_main_kernel<<<nblocks, TPB, 0, stream>>>(x, Mt, out);
}

// Round 6
// 102.769 us; speedup vs baseline: 1.1975x; 1.1975x over previous
//
#include <hip/hip_runtime.h>
#include <hip/hip_bf16.h>

// out[b,n] = sum_k x[b,k] * M[k,n],  M[k,n] = sign(k, k^n) * w[k^n]
// P=6,Q=0,R=0 -> metric all +1, sign = reorder parity only.
//
// out^T = M^T (A) @ x^T (B) via mfma_f32_16x16x32_bf16 (layout validated
// round 4, absmax 0.25):
//   A-frag: lane l -> row a=l&15, k=(l>>4)*8+e  (frag-ordered in d_ws)
//   B-frag: lane l -> col b=l&15, k=(l>>4)*8+e  = 8 contiguous k of x row b
//   C/D   : D[m=(l>>4)*4+reg][n=l&15] -> lane's 4 regs = 4 consecutive out
//           cols of one batch row; 16-lane groups complete full 64B lines.
//
// x is staged f32 into LDS via global_load_lds dwordx4 DMA (no VGPR round
// trip), bf16-converted at fragment read. 32B-granule XOR swizzle applied
// via pre-swizzled GLOBAL source (DMA dest must stay linear, m104/m173).

#define DIM 64
#define TPB 256            // 4 waves
#define ROWS 64            // rows per block; LDS = 64*256B = 16 KB -> 8 blk/CU

typedef __attribute__((ext_vector_type(8))) short  bf16x8;
typedef __attribute__((ext_vector_type(4))) float  f32x4;

typedef const unsigned int __attribute__((address_space(1)))* gu32p;
typedef unsigned int __attribute__((address_space(3)))* su32p;

__device__ __forceinline__ unsigned short f2bf(float v) {
    __hip_bfloat16 hb = __float2bfloat16(v);
    return *reinterpret_cast<unsigned short*>(&hb);
}

// Mt[(kc*4+ab)*64 + lane] = 16B A-fragment slice for mfma block (kc, ab):
// elem e -> A[a = ab*16 + (l&15)][k = kc*32 + (l>>4)*8 + e], A = M^T.
__global__ void build_Mt(const float* __restrict__ w, unsigned short* __restrict__ Mt) {
    int t = threadIdx.x + blockIdx.x * blockDim.x;   // 0..4095
    if (t >= 8 * 64 * 8) return;
    int f  = t >> 9;
    int kc = f >> 2, ab = f & 3;
    int rem = t & 511;
    int l = rem >> 3, e = rem & 7;
    int k = kc * 32 + ((l >> 4) << 3) + e;
    int a = (ab << 4) + (l & 15);
    int j = k ^ a;
    int aa = k >> 1, cnt = 0;
    while (aa) { cnt += __popc(aa & j); aa >>= 1; }
    float v = (cnt & 1) ? -w[j] : w[j];
    Mt[t] = f2bf(v);
}

__global__ __launch_bounds__(TPB, 8)   // 8 blocks/CU = 32 waves/CU (VGPR<=64)
void gp_main_kernel(const float* __restrict__ x,
                    const unsigned short* __restrict__ Mt,
                    float* __restrict__ out) {
    __shared__ float xs[ROWS * DIM];     // 16 KB, f32, granule-swizzled rows

    const int tid  = threadIdx.x;
    const int lane = tid & 63;
    const int wv   = tid >> 6;
    const int r15  = lane & 15;
    const int g    = lane >> 4;          // k-quarter within fragment

    const long long rowbase = (long long)blockIdx.x * ROWS;
    const float4* __restrict__ xin = (const float4*)x;

    // ---- stage: 4x global_load_lds dwordx4 per thread, linear LDS dest ----
    // LDS f4-slot idx holds row=idx>>4, granule gr=(idx&15)>>1, half=idx&1;
    // content = source granule c = gr ^ (row&7)  (inverse == forward, involution)
    #pragma unroll
    for (int it = 0; it < 4; ++it) {
        int idx  = it * TPB + tid;           // 0..1023 float4 slots
        int row  = idx >> 4;
        int f4   = idx & 15;
        int c    = ((f4 >> 1) ^ (row & 7));
        long long src = (rowbase + row) * 16 + c * 2 + (f4 & 1);
        __builtin_amdgcn_global_load_lds((gu32p)(xin + src),
                                         (su32p)&xs[idx * 4], 16, 0, 0);
    }

    // ---- A-fragments (tiny, L2-resident) while DMA is in flight ----
    bf16x8 af[2][4];
    const bf16x8* __restrict__ Mtv = (const bf16x8*)Mt;
    #pragma unroll
    for (int kc = 0; kc < 2; ++kc)
        #pragma unroll
        for (int ab = 0; ab < 4; ++ab)
            af[kc][ab] = Mtv[(kc * 4 + ab) * 64 + lane];

    __syncthreads();   // compiler drains vmcnt+lgkmcnt before barrier

    // ---- compute: wave wv owns rows [wv*16, wv*16+16) ----
    const int r_loc = wv * 16 + r15;
    bf16x8 bfr[2];
    #pragma unroll
    for (int kc = 0; kc < 2; ++kc) {
        int s = (kc * 4 + g) ^ (r_loc & 7);          // swizzled 32B granule
        const float* src = &xs[r_loc * DIM + s * 8];
        float4 lo = *reinterpret_cast<const float4*>(src);       // ds_read_b128
        float4 hi = *reinterpret_cast<const float4*>(src + 4);   // ds_read_b128
        bf16x8 t;
        t[0] = (short)f2bf(lo.x); t[1] = (short)f2bf(lo.y);
        t[2] = (short)f2bf(lo.z); t[3] = (short)f2bf(lo.w);
        t[4] = (short)f2bf(hi.x); t[5] = (short)f2bf(hi.y);
        t[6] = (short)f2bf(hi.z); t[7] = (short)f2bf(hi.w);
        bfr[kc] = t;
    }

    f32x4 acc[4];
    #pragma unroll
    for (int ab = 0; ab < 4; ++ab) acc[ab] = (f32x4){0.f, 0.f, 0.f, 0.f};
    #pragma unroll
    for (int kc = 0; kc < 2; ++kc)
        #pragma unroll
        for (int ab = 0; ab < 4; ++ab)
            acc[ab] = __builtin_amdgcn_mfma_f32_16x16x32_bf16(
                af[kc][ab], bfr[kc], acc[ab], 0, 0, 0);

    // ---- store: full 64B lines per 16-lane group ----
    float4* __restrict__ outp = (float4*)out;
    const long long rg = rowbase + r_loc;
    #pragma unroll
    for (int ab = 0; ab < 4; ++ab)
        outp[rg * 16 + ab * 4 + g] =
            make_float4(acc[ab][0], acc[ab][1], acc[ab][2], acc[ab][3]);
}

extern "C" void kernel_launch(void* const* d_in, const int* in_sizes, int n_in,
                              void* d_out, int out_size, void* d_ws, size_t ws_size,
                              hipStream_t stream) {
    const float* x = (const float*)d_in[0];
    const float* w = (const float*)d_in[1];
    float* out = (float*)d_out;
    unsigned short* Mt = (unsigned short*)d_ws;   // 8 KB frag-ordered M^T

    int nrows = in_sizes[0] / DIM;                // 1048576
    int nblocks = nrows / ROWS;                   // 16384 (exact)

    build_Mt<<<16, 256, 0, stream>>>(w, Mt);
    gp_main_kernel<<<nblocks, TPB, 0, stream>>>(x, Mt, out);
}